// Round 2
// baseline (471.188 us; speedup 1.0000x reference)
//
#include <hip/hip_runtime.h>

// LDW lifting-wavelet 2x2 downsample, fused single pass, vectorized.
// x: [16,64,257,257] f32 -> out: [16,256,128,128] f32
// Bands along channel: [ll(0:64), hl(64:128), lh(128:192), hh(192:256)].
//
// Key facts exploited:
//  - input row base float-index parity == (p + r) & 1 (257^2 and 257 are odd),
//    and p is uniform per block -> compile-time-cloned aligned float2 loads.
//  - output rows are 16B aligned -> float4 nontemporal stores (pure streaming).
//  - vertical lift intermediates carried in registers -> each input row read once.

#define B_ 16
#define C_ 64
#define H_ 257
#define W_ 257
#define HO_ 128
#define WO_ 128
#define SEGS 8
#define SEG_ROWS (HO_ / SEGS)   // 16
#define NP (B_ * C_)            // 1024 planes

typedef float f32x4 __attribute__((ext_vector_type(4)));

// Load 9 consecutive floats from a row whose base float-index parity is PAR.
template<int PAR>
__device__ __forceinline__ void load9(const float* __restrict__ rp, float* a) {
    if constexpr (PAR == 0) {
        // even base -> 8B-aligned pairs at +0,+2,+4,+6, scalar tail
        float2 v0 = *reinterpret_cast<const float2*>(rp + 0);
        float2 v1 = *reinterpret_cast<const float2*>(rp + 2);
        float2 v2 = *reinterpret_cast<const float2*>(rp + 4);
        float2 v3 = *reinterpret_cast<const float2*>(rp + 6);
        a[0] = v0.x; a[1] = v0.y; a[2] = v1.x; a[3] = v1.y;
        a[4] = v2.x; a[5] = v2.y; a[6] = v3.x; a[7] = v3.y;
        a[8] = rp[8];
    } else {
        // odd base -> scalar head, aligned pairs at +1,+3,+5,+7
        a[0] = rp[0];
        float2 v0 = *reinterpret_cast<const float2*>(rp + 1);
        float2 v1 = *reinterpret_cast<const float2*>(rp + 3);
        float2 v2 = *reinterpret_cast<const float2*>(rp + 5);
        float2 v3 = *reinterpret_cast<const float2*>(rp + 7);
        a[1] = v0.x; a[2] = v0.y; a[3] = v1.x; a[4] = v1.y;
        a[5] = v2.x; a[6] = v2.y; a[7] = v3.x; a[8] = v3.y;
    }
}

// PE = parity of EVEN input rows for this plane (= p & 1). Odd rows are PE^1.
template<int PE>
__device__ __forceinline__ void run_seg(
    const float* __restrict__ row0,   // &x[p][2*ho0][8*wt]
    float* __restrict__ o_ll,         // &out[b][0*C+c][ho0][4*wt]
    float lh0, float lh1, float hh0, float hh1,
    float lv0, float lv1, float hv0, float hv1)
{
    const long BAND = (long)C_ * HO_ * WO_;   // 64*16384 floats between bands
    float* o_hl = o_ll + BAND;
    float* o_lh = o_ll + 2 * BAND;
    float* o_hh = o_ll + 3 * BAND;

    // prime: horizontal lift of the carried even row (r = 2*ho0)
    float a[9];
    load9<PE>(row0, a);
    float xl0[4], xh0[4];
    #pragma unroll
    for (int j = 0; j < 4; ++j) {
        xl0[j] = lh0 * a[2 * j]     + lh1 * a[2 * j + 1];
        xh0[j] = hh0 * a[2 * j + 1] + hh1 * a[2 * j + 2];
    }

    const float* rp = row0 + W_;   // odd row 2*ho0+1

    #pragma unroll 4
    for (int i = 0; i < SEG_ROWS; ++i) {
        float bb[9], cc[9];
        load9<PE ^ 1>(rp, bb);          // odd row
        load9<PE>(rp + W_, cc);         // even row
        rp += 2 * W_;

        float ll[4], hl[4], lhv[4], hh[4];
        #pragma unroll
        for (int j = 0; j < 4; ++j) {
            const float xl1 = lh0 * bb[2 * j]     + lh1 * bb[2 * j + 1];
            const float xh1 = hh0 * bb[2 * j + 1] + hh1 * bb[2 * j + 2];
            const float xl2 = lh0 * cc[2 * j]     + lh1 * cc[2 * j + 1];
            const float xh2 = hh0 * cc[2 * j + 1] + hh1 * cc[2 * j + 2];
            ll[j]  = lv0 * xl0[j] + lv1 * xl1;
            hl[j]  = hv0 * xl1    + hv1 * xl2;
            lhv[j] = lv0 * xh0[j] + lv1 * xh1;
            hh[j]  = hv0 * xh1    + hv1 * xh2;
            xl0[j] = xl2;
            xh0[j] = xh2;
        }
        f32x4 vll = {ll[0], ll[1], ll[2], ll[3]};
        f32x4 vhl = {hl[0], hl[1], hl[2], hl[3]};
        f32x4 vlh = {lhv[0], lhv[1], lhv[2], lhv[3]};
        f32x4 vhh = {hh[0], hh[1], hh[2], hh[3]};
        __builtin_nontemporal_store(vll, reinterpret_cast<f32x4*>(o_ll));
        __builtin_nontemporal_store(vhl, reinterpret_cast<f32x4*>(o_hl));
        __builtin_nontemporal_store(vlh, reinterpret_cast<f32x4*>(o_lh));
        __builtin_nontemporal_store(vhh, reinterpret_cast<f32x4*>(o_hh));
        o_ll += WO_; o_hl += WO_; o_lh += WO_; o_hh += WO_;
    }
}

__global__ __launch_bounds__(256) void ldw_down_kernel(
    const float* __restrict__ x,
    const float* __restrict__ low_h,
    const float* __restrict__ high_h,
    const float* __restrict__ low_v,
    const float* __restrict__ high_v,
    float* __restrict__ out)
{
    const float lh0 = low_h[0],  lh1 = low_h[1];
    const float hh0 = high_h[0], hh1 = high_h[1];
    const float lv0 = low_v[0],  lv1 = low_v[1];
    const float hv0 = high_v[0], hv1 = high_v[1];

    const int p   = blockIdx.x;            // one plane per block (1024 blocks)
    const int t   = threadIdx.x;
    const int wt  = t & 31;                // 4-wide output tile index (32 tiles)
    const int seg = t >> 5;                // 8 row segments of 16 output rows

    const int b = p >> 6;
    const int c = p & (C_ - 1);
    const int ho0 = seg * SEG_ROWS;

    const float* row0 = x + (long)p * (H_ * W_) + (long)(2 * ho0) * W_ + 8 * wt;
    float* o_ll = out + (long)b * (4 * C_) * (HO_ * WO_)
                      + (long)c * (HO_ * WO_)
                      + (long)ho0 * WO_ + 4 * wt;

    if ((p & 1) == 0)
        run_seg<0>(row0, o_ll, lh0, lh1, hh0, hh1, lv0, lv1, hv0, hv1);
    else
        run_seg<1>(row0, o_ll, lh0, lh1, hh0, hh1, lv0, lv1, hv0, hv1);
}

extern "C" void kernel_launch(void* const* d_in, const int* in_sizes, int n_in,
                              void* d_out, int out_size, void* d_ws, size_t ws_size,
                              hipStream_t stream) {
    const float* x      = (const float*)d_in[0];
    const float* low_h  = (const float*)d_in[1];
    const float* high_h = (const float*)d_in[2];
    const float* low_v  = (const float*)d_in[3];
    const float* high_v = (const float*)d_in[4];
    float* out = (float*)d_out;

    ldw_down_kernel<<<NP, 256, 0, stream>>>(x, low_h, high_h, low_v, high_v, out);
}

// Round 3
// 467.772 us; speedup vs baseline: 1.0073x; 1.0073x over previous
//
#include <hip/hip_runtime.h>

// LDW lifting-wavelet 2x2 downsample, LDS-staged fused pass.
// x: [16,64,257,257] f32 -> out: [16,256,128,128] f32
// Bands along channel: [ll, hl, lh, hh] blocks of 64.
//
// Design (round 3):
//  - Global reads PERFECTLY coalesced: a wave stages one input row; lane L
//    loads floats {L, L+64, L+128, L+192} (+ lane0 tail f256) -> each
//    instruction is a 256B contiguous wave access.
//  - 8-slot LDS ring of padded rows (8*264 floats = 8.4 KB); stencil (9 floats
//    per output, stride-2 lanes) reads from LDS, where the 4-way bank alias
//    costs ~1.6x of a tiny LDS budget instead of wrecking the global path.
//  - Staging loads are issued BEFORE the compute phase (async-stage split):
//    HBM latency hides under the lifting math; ds_write after the barrier.
//  - Grid 8192 blocks (plane x 8 slabs), __launch_bounds__(256,8) -> up to
//    32 waves/CU resident vs 16 before.

#define B_ 16
#define C_ 64
#define H_ 257
#define W_ 257
#define HO_ 128
#define WO_ 128
#define OROWS 16                 // output rows per block
#define SLABS (HO_ / OROWS)      // 8
#define PADW 264                 // LDS row pitch (floats)
#define NSLOT 8

__global__ __launch_bounds__(256, 8) void ldw_down_kernel(
    const float* __restrict__ x,
    const float* __restrict__ low_h,
    const float* __restrict__ high_h,
    const float* __restrict__ low_v,
    const float* __restrict__ high_v,
    float* __restrict__ out)
{
    __shared__ float lds[NSLOT * PADW];

    const float lh0 = low_h[0],  lh1 = low_h[1];
    const float hh0 = high_h[0], hh1 = high_h[1];
    const float lv0 = low_v[0],  lv1 = low_v[1];
    const float hv0 = high_v[0], hv1 = high_v[1];

    const int bid  = blockIdx.x;
    const int p    = bid >> 3;            // plane 0..1023
    const int slab = bid & (SLABS - 1);
    const int ho0  = slab * OROWS;

    const int t    = threadIdx.x;
    const int wave = t >> 6;
    const int lane = t & 63;
    const int wo   = t & 127;             // output col
    const int orow = t >> 7;              // 0/1: which of the 2 rows this iter

    // input slab base: rows 2*ho0 .. 2*ho0+32 (33 rows needed)
    const float* xrow0 = x + (long)p * (H_ * W_) + (long)(2 * ho0) * W_;

    const int b = p >> 6;
    const int c = p & (C_ - 1);
    const long BAND = (long)C_ * HO_ * WO_;
    float* o_ll = out + (long)b * 4 * BAND + (long)c * (HO_ * WO_);
    float* o_hl = o_ll + BAND;
    float* o_lh = o_ll + 2 * BAND;
    float* o_hh = o_ll + 3 * BAND;

    // ---- prologue: stage rows 0..7 (wave w does rows w and w+4) ----
    #pragma unroll
    for (int k = 0; k < 2; ++k) {
        const int rel = wave + 4 * k;
        const float* src = xrow0 + (long)rel * W_;
        float* dst = &lds[(rel & (NSLOT - 1)) * PADW];
        float v0 = src[lane];
        float v1 = src[lane + 64];
        float v2 = src[lane + 128];
        float v3 = src[lane + 192];
        dst[lane]       = v0;
        dst[lane + 64]  = v1;
        dst[lane + 128] = v2;
        dst[lane + 192] = v3;
        if (lane == 0) dst[256] = src[256];
    }
    __syncthreads();

    // ---- main loop: 8 iterations, 2 output rows each ----
    #pragma unroll
    for (int i = 0; i < 8; ++i) {
        // 1. prefetch next staging row into registers (rows 4i+8 .. 4i+11)
        const int rel = 4 * i + 8 + wave;
        const bool do_stage = (rel <= 32);
        float v0, v1, v2, v3, vt;
        const float* src = xrow0 + (long)rel * W_;
        if (do_stage) {
            v0 = src[lane];
            v1 = src[lane + 64];
            v2 = src[lane + 128];
            v3 = src[lane + 192];
            if (lane == 0) vt = src[256];
        }

        // 2. compute from LDS rows 4i+2*orow .. +2
        const int base = 4 * i + 2 * orow;
        float xl[3], xh[3];
        #pragma unroll
        for (int r = 0; r < 3; ++r) {
            const float* rp = &lds[((base + r) & (NSLOT - 1)) * PADW + 2 * wo];
            const float2 f01 = *reinterpret_cast<const float2*>(rp);
            const float  f2  = rp[2];
            xl[r] = lh0 * f01.x + lh1 * f01.y;
            xh[r] = hh0 * f01.y + hh1 * f2;
        }
        const float r_ll = lv0 * xl[0] + lv1 * xl[1];
        const float r_hl = hv0 * xl[1] + hv1 * xl[2];
        const float r_lh = lv0 * xh[0] + lv1 * xh[1];
        const float r_hh = hv0 * xh[1] + hv1 * xh[2];

        const long o = (long)(ho0 + 2 * i + orow) * WO_ + wo;
        __builtin_nontemporal_store(r_ll, o_ll + o);
        __builtin_nontemporal_store(r_hl, o_hl + o);
        __builtin_nontemporal_store(r_lh, o_lh + o);
        __builtin_nontemporal_store(r_hh, o_hh + o);

        // 3. publish staged rows for the next iteration
        __syncthreads();
        if (do_stage) {
            float* dst = &lds[(rel & (NSLOT - 1)) * PADW];
            dst[lane]       = v0;
            dst[lane + 64]  = v1;
            dst[lane + 128] = v2;
            dst[lane + 192] = v3;
            if (lane == 0) dst[256] = vt;
        }
        __syncthreads();
    }
}

extern "C" void kernel_launch(void* const* d_in, const int* in_sizes, int n_in,
                              void* d_out, int out_size, void* d_ws, size_t ws_size,
                              hipStream_t stream) {
    const float* x      = (const float*)d_in[0];
    const float* low_h  = (const float*)d_in[1];
    const float* high_h = (const float*)d_in[2];
    const float* low_v  = (const float*)d_in[3];
    const float* high_v = (const float*)d_in[4];
    float* out = (float*)d_out;

    const int grid = B_ * C_ * SLABS;   // 8192 blocks
    ldw_down_kernel<<<grid, 256, 0, stream>>>(x, low_h, high_h, low_v, high_v, out);
}